// Round 15
// baseline (299.389 us; speedup 1.0000x reference)
//
#include <hip/hip_runtime.h>
#include <hip/hip_bf16.h>

// B=2, S=2048, D=1024, H=16, dk=64. INPUTS FP32, OUTPUT FP32. M = 4096 rows.
// ROUND 15: 16-row attention strips (1 wave = 16 q-rows), 4096 waves.
// GEMMs/convs/vtrans unchanged from r13/r14.

typedef __bf16 bf16x8 __attribute__((ext_vector_type(8)));
typedef float f32x4 __attribute__((ext_vector_type(4)));

#define LOG2E 1.4426950408889634f

__device__ __forceinline__ ushort f2bf(float f) {
  __hip_bfloat16 h = __float2bfloat16(f);
  return __builtin_bit_cast(ushort, h);
}

__device__ __forceinline__ uint pack2(float a, float b) {
  return (uint)f2bf(a) | ((uint)f2bf(b) << 16);
}

__device__ __forceinline__ void gl2lds16(const ushort* g, ushort* l) {
  __builtin_amdgcn_global_load_lds(
      (const __attribute__((address_space(1))) void*)g,
      (__attribute__((address_space(3))) void*)l, 16, 0, 0);
}

// ------------------------------------------------------------ fp32 -> bf16
__global__ __launch_bounds__(256) void conv_bf16(const float* __restrict__ src,
                                                 ushort* __restrict__ dst,
                                                 int n8) {
  int i = blockIdx.x * 256 + threadIdx.x;
  if (i >= n8) return;
  const float4* s = (const float4*)src + (long)i * 2;
  float4 a = s[0], b = s[1];
  uint4 pk = {pack2(a.x, a.y), pack2(a.z, a.w), pack2(b.x, b.y), pack2(b.z, b.w)};
  ((uint4*)dst)[i] = pk;
}

// ---------------------------------------------------------------- GEMM (NT)
// (unchanged from r13 — validated)
__global__ __launch_bounds__(256) void gemm_bt(
    const ushort* __restrict__ A, const ushort* __restrict__ B, int nbn,
    ushort* __restrict__ qb, ushort* __restrict__ kb, ushort* __restrict__ vb,
    float* __restrict__ Cout, int epi) {
  __shared__ __align__(16) ushort As[128 * 64];
  __shared__ __align__(16) ushort Bs[128 * 64];
  const int tid = threadIdx.x;
  const int w = tid >> 6, lane = tid & 63, quad = lane >> 4, lc = lane & 15;
  const int bid = blockIdx.x;
  const int bm = bid / nbn, bn = bid % nbn;
  const int wm = (w & 1) * 64, wn = (w >> 1) * 64;

  f32x4 acc[4][4] = {};

  const ushort* Ag = A + (long)bm * 131072;
  const ushort* Bg = B + (long)bn * 131072;

  for (int k0 = 0; k0 < 1024; k0 += 64) {
    __syncthreads();
    for (int i = 0; i < 4; ++i) {
      int u = i * 256 + tid;
      int row = u >> 3, ch = u & 7;
      gl2lds16(Ag + row * 1024 + k0 + ch * 8, &As[(i * 256 + w * 64) * 8]);
      gl2lds16(Bg + row * 1024 + k0 + ch * 8, &Bs[(i * 256 + w * 64) * 8]);
    }
    __builtin_amdgcn_s_waitcnt(0);
    __syncthreads();
    for (int kc = 0; kc < 2; ++kc) {
      bf16x8 af[4], bfr[4];
      for (int t = 0; t < 4; ++t)
        af[t] = *(const bf16x8*)&As[(wm + t * 16 + lc) * 64 + kc * 32 + quad * 8];
      for (int t = 0; t < 4; ++t)
        bfr[t] = *(const bf16x8*)&Bs[(wn + t * 16 + lc) * 64 + kc * 32 + quad * 8];
      for (int rt = 0; rt < 4; ++rt)
        for (int ct = 0; ct < 4; ++ct)
          acc[rt][ct] = __builtin_amdgcn_mfma_f32_16x16x32_bf16(
              af[rt], bfr[ct], acc[rt][ct], 0, 0, 0);
    }
  }

  const int row0 = bm * 128 + wm;
  if (epi == 0) {
    const int e0 = bn * 128;
    const int g = e0 >> 10;
    const int h = ((e0 & 1023) + wn) >> 6;
    const float qs = (g == 0) ? 0.125f * LOG2E : 1.0f;
    ushort* dst = (g == 0) ? qb : ((g == 1) ? kb : vb);
    const float ang = powf(1e-4f, (float)lc * (1.0f / 15.0f));
    for (int rt = 0; rt < 4; ++rt) {
      for (int r = 0; r < 4; ++r) {
        int m = row0 + rt * 16 + quad * 4 + r;
        int srow = m & 2047;
        int b = m >> 11;
        if (g < 2) {
          float theta = (float)srow * ang;
          float sn, c;
          sincosf(theta, &sn, &c);
          float x1 = acc[rt][0][r], x2 = acc[rt][2][r];
          acc[rt][0][r] = x1 * c - x2 * sn;
          acc[rt][2][r] = x1 * sn + x2 * c;
        }
        ushort* drow = dst + (((long)b * 16 + h) * 2048 + srow) * 64;
        for (int ct = 0; ct < 4; ++ct)
          drow[ct * 16 + lc] = f2bf(acc[rt][ct][r] * qs);
      }
    }
  } else {
    for (int rt = 0; rt < 4; ++rt)
      for (int r = 0; r < 4; ++r) {
        int m = row0 + rt * 16 + quad * 4 + r;
        float* drow = Cout + (long)m * 1024 + bn * 128 + wn;
        for (int ct = 0; ct < 4; ++ct)
          drow[ct * 16 + lc] = acc[rt][ct][r];
      }
  }
}

// ----------------------------------------------------------- V transpose
__global__ __launch_bounds__(256) void vtrans(const ushort* __restrict__ vb,
                                              ushort* __restrict__ vt) {
  __shared__ __align__(16) ushort T[64 * 72];
  const int tid = threadIdx.x, sc = blockIdx.x, bh = blockIdx.y;
  const ushort* src = vb + ((long)bh * 2048 + sc * 64) * 64;
  for (int i = 0; i < 2; ++i) {
    int u = i * 256 + tid;
    int row = u >> 3, ch = u & 7;
    uint4 vv = *(const uint4*)&src[row * 64 + ch * 8];
    const ushort* e = (const ushort*)&vv;
    for (int t = 0; t < 8; ++t) T[(ch * 8 + t) * 72 + row] = e[t];
  }
  __syncthreads();
  for (int i = 0; i < 2; ++i) {
    int u = i * 256 + tid;
    int d = u >> 3, ch = u & 7;
    uint4 vv = *(const uint4*)&T[d * 72 + ch * 8];
    *(uint4*)&vt[((long)bh * 64 + d) * 2048 + sc * 64 + ch * 8] = vv;
  }
}

// ---------------------------------------------------------------- attention
// ONE WAVE = 16 q-rows (one q-tile). strip s in [0,128): qtbase = s*16,
// jmax = s>>2, rowoff = (s&3)*16. Transposed scores, in-register softmax,
// P via swizzled wave-private LDS.
__global__ __launch_bounds__(64) void attn_kernel(
    const ushort* __restrict__ qb, const ushort* __restrict__ kb,
    const ushort* __restrict__ vt, ushort* __restrict__ out) {
  __shared__ __align__(16) ushort Psw[16 * 64];  // 2 KB, wave-private
  const int lane = threadIdx.x;
  const int quad = lane >> 4, lc = lane & 15, l7 = lc & 7;
  const int bid = blockIdx.x;                   // 0..4095
  const int s = 127 - (bid >> 5);               // strip, big-work first
  const int bh = bid & 31;
  const int bidx = bh >> 4, h = bh & 15;
  const int qtbase = s * 16;

  bf16x8 qf[2];
  for (int kc = 0; kc < 2; ++kc)
    qf[kc] = *(const bf16x8*)&qb[((long)bh * 2048 + qtbase + lc) * 64 +
                                 kc * 32 + quad * 8];

  f32x4 oacc[4] = {};
  float m_ = -3.0e38f, l_ = 0.0f;

  const ushort* K = kb + (long)bh * 2048 * 64;
  const ushort* Vt = vt + (long)bh * 64 * 2048;
  const int jmax = s >> 2;
  const int rowoff = (s & 3) * 16;

  for (int j = 0; j <= jmax; ++j) {
    f32x4 sacc[4] = {};
    for (int kc = 0; kc < 2; ++kc) {
      bf16x8 kf[4];
      for (int kt = 0; kt < 4; ++kt)
        kf[kt] = *(const bf16x8*)&K[(long)(j * 64 + kt * 16 + lc) * 64 +
                                    kc * 32 + quad * 8];
      for (int kt = 0; kt < 4; ++kt)
        sacc[kt] = __builtin_amdgcn_mfma_f32_16x16x32_bf16(
            kf[kt], qf[kc], sacc[kt], 0, 0, 0);
    }
    if (j == jmax) {  // causal partial tile
      int rowrel = rowoff + lc;
      for (int kt = 0; kt < 4; ++kt)
        for (int r = 0; r < 4; ++r)
          if (kt * 16 + quad * 4 + r > rowrel) sacc[kt][r] = -1.0e30f;
    }
    // online softmax: 16 keys in-register per lane + cross-quad shfl
    float vm = sacc[0][0];
    for (int kt = 0; kt < 4; ++kt)
      for (int r = 0; r < 4; ++r) vm = fmaxf(vm, sacc[kt][r]);
    vm = fmaxf(vm, __shfl_xor(vm, 16, 64));
    vm = fmaxf(vm, __shfl_xor(vm, 32, 64));
    float mn = fmaxf(m_, vm);
    float alpha = exp2f(m_ - mn);
    m_ = mn;
    float rs = 0.0f;
    float p[4][4];
    for (int kt = 0; kt < 4; ++kt)
      for (int r = 0; r < 4; ++r) {
        p[kt][r] = exp2f(sacc[kt][r] - mn);
        rs += p[kt][r];
      }
    rs += __shfl_xor(rs, 16, 64);
    rs += __shfl_xor(rs, 32, 64);
    l_ = l_ * alpha + rs;
    for (int mt = 0; mt < 4; ++mt) oacc[mt] *= alpha;
    for (int kt = 0; kt < 4; ++kt) {
      uint2 pk = {pack2(p[kt][0], p[kt][1]), pack2(p[kt][2], p[kt][3])};
      *(uint2*)&Psw[lc * 64 + (((kt * 2 + (quad >> 1)) ^ l7) << 3) +
                    ((quad & 1) << 2)] = pk;
    }
    __threadfence_block();
    for (int kc = 0; kc < 2; ++kc) {
      bf16x8 vf[4], pf;
      for (int mt = 0; mt < 4; ++mt)
        vf[mt] = *(const bf16x8*)&Vt[(long)(mt * 16 + lc) * 2048 + j * 64 +
                                     kc * 32 + quad * 8];
      pf = *(const bf16x8*)&Psw[lc * 64 + (((kc * 4 + quad) ^ l7) << 3)];
      for (int mt = 0; mt < 4; ++mt)
        oacc[mt] = __builtin_amdgcn_mfma_f32_16x16x32_bf16(
            vf[mt], pf, oacc[mt], 0, 0, 0);
    }
    __threadfence_block();
  }

  // epilogue: O^T/l -> LDS (same swizzle) -> coalesced bf16 rows of ao
  {
    float linv = 1.0f / l_;
    for (int mt = 0; mt < 4; ++mt) {
      uint2 pk = {pack2(oacc[mt][0] * linv, oacc[mt][1] * linv),
                  pack2(oacc[mt][2] * linv, oacc[mt][3] * linv)};
      *(uint2*)&Psw[lc * 64 + (((mt * 2 + (quad >> 1)) ^ l7) << 3) +
                    ((quad & 1) << 2)] = pk;
    }
  }
  __threadfence_block();
  {
    int r2 = lane >> 2;              // local q-row 0..15
    long mrow = (long)bidx * 2048 + qtbase + r2;
    for (int c = 0; c < 2; ++c) {
      int c8 = (lane & 3) * 2 + c;   // d-chunk 0..7
      uint4 vv = *(const uint4*)&Psw[r2 * 64 + ((c8 ^ (r2 & 7)) << 3)];
      *(uint4*)&out[mrow * 1024 + h * 64 + c8 * 8] = vv;
    }
  }
}

extern "C" void kernel_launch(void* const* d_in, const int* in_sizes, int n_in,
                              void* d_out, int out_size, void* d_ws, size_t ws_size,
                              hipStream_t stream) {
  const float* x = nullptr;     // 4194304 elems
  const float* Wqkv = nullptr;  // 3145728 elems
  const float* Wo = nullptr;    // 1048576 elems
  for (int i = 0; i < n_in; ++i) {
    if (in_sizes[i] == 4194304) x = (const float*)d_in[i];
    else if (in_sizes[i] == 3145728) Wqkv = (const float*)d_in[i];
    else if (in_sizes[i] == 1048576) Wo = (const float*)d_in[i];
  }
  float* out = (float*)d_out;  // [4096,1024] fp32 (16 MiB)

  // Workspace (32 MiB) + d_out-as-scratch timeline (same as r13):
  ushort* qbuf = (ushort*)d_ws;
  ushort* kbuf = qbuf + 4194304;
  ushort* vbuf = kbuf + 4194304;
  ushort* vtb  = vbuf + 4194304;
  ushort* wqkvh = vtb;                 // [24..30) before vtrans
  ushort* woh  = qbuf;                 // [0..2) after attn
  ushort* ao   = vbuf;                 // aliases vbuf
  ushort* xh   = (ushort*)d_out;       // x_bf16 in d_out scratch

  conv_bf16<<<2048, 256, 0, stream>>>(x, xh, 524288);
  conv_bf16<<<1536, 256, 0, stream>>>(Wqkv, wqkvh, 393216);
  gemm_bt<<<768, 256, 0, stream>>>(xh, wqkvh, 24, qbuf, kbuf, vbuf, nullptr, 0);
  vtrans<<<dim3(32, 32), 256, 0, stream>>>(vbuf, vtb);
  attn_kernel<<<4096, 64, 0, stream>>>(qbuf, kbuf, vtb, ao);
  conv_bf16<<<512, 256, 0, stream>>>(Wo, woh, 131072);
  gemm_bt<<<256, 256, 0, stream>>>(ao, woh, 8, nullptr, nullptr, nullptr, out, 1);
}

// Round 16
// 251.997 us; speedup vs baseline: 1.1881x; 1.1881x over previous
//
#include <hip/hip_runtime.h>
#include <hip/hip_bf16.h>

// B=2, S=2048, D=1024, H=16, dk=64. INPUTS FP32, OUTPUT FP32. M = 4096 rows.
// ROUND 16: r14 geometry (32-row waves) + FIXED-MAX softmax (p=exp2(s-16),
// no running max / alpha / rescale — scores bounded ~|4|) + parity-double-
// buffered P scratch (one fence per iter instead of two).

typedef __bf16 bf16x8 __attribute__((ext_vector_type(8)));
typedef float f32x4 __attribute__((ext_vector_type(4)));

#define LOG2E 1.4426950408889634f
#define SMAX 16.0f  // fixed softmax shift; scores are |s| <~ 4 by construction

__device__ __forceinline__ ushort f2bf(float f) {
  __hip_bfloat16 h = __float2bfloat16(f);
  return __builtin_bit_cast(ushort, h);
}

__device__ __forceinline__ uint pack2(float a, float b) {
  return (uint)f2bf(a) | ((uint)f2bf(b) << 16);
}

__device__ __forceinline__ void gl2lds16(const ushort* g, ushort* l) {
  __builtin_amdgcn_global_load_lds(
      (const __attribute__((address_space(1))) void*)g,
      (__attribute__((address_space(3))) void*)l, 16, 0, 0);
}

// ------------------------------------------------------------ fp32 -> bf16
__global__ __launch_bounds__(256) void conv_bf16(const float* __restrict__ src,
                                                 ushort* __restrict__ dst,
                                                 int n8) {
  int i = blockIdx.x * 256 + threadIdx.x;
  if (i >= n8) return;
  const float4* s = (const float4*)src + (long)i * 2;
  float4 a = s[0], b = s[1];
  uint4 pk = {pack2(a.x, a.y), pack2(a.z, a.w), pack2(b.x, b.y), pack2(b.z, b.w)};
  ((uint4*)dst)[i] = pk;
}

// ---------------------------------------------------------------- GEMM (NT)
// (unchanged from r13 — validated)
__global__ __launch_bounds__(256) void gemm_bt(
    const ushort* __restrict__ A, const ushort* __restrict__ B, int nbn,
    ushort* __restrict__ qb, ushort* __restrict__ kb, ushort* __restrict__ vb,
    float* __restrict__ Cout, int epi) {
  __shared__ __align__(16) ushort As[128 * 64];
  __shared__ __align__(16) ushort Bs[128 * 64];
  const int tid = threadIdx.x;
  const int w = tid >> 6, lane = tid & 63, quad = lane >> 4, lc = lane & 15;
  const int bid = blockIdx.x;
  const int bm = bid / nbn, bn = bid % nbn;
  const int wm = (w & 1) * 64, wn = (w >> 1) * 64;

  f32x4 acc[4][4] = {};

  const ushort* Ag = A + (long)bm * 131072;
  const ushort* Bg = B + (long)bn * 131072;

  for (int k0 = 0; k0 < 1024; k0 += 64) {
    __syncthreads();
    for (int i = 0; i < 4; ++i) {
      int u = i * 256 + tid;
      int row = u >> 3, ch = u & 7;
      gl2lds16(Ag + row * 1024 + k0 + ch * 8, &As[(i * 256 + w * 64) * 8]);
      gl2lds16(Bg + row * 1024 + k0 + ch * 8, &Bs[(i * 256 + w * 64) * 8]);
    }
    __builtin_amdgcn_s_waitcnt(0);
    __syncthreads();
    for (int kc = 0; kc < 2; ++kc) {
      bf16x8 af[4], bfr[4];
      for (int t = 0; t < 4; ++t)
        af[t] = *(const bf16x8*)&As[(wm + t * 16 + lc) * 64 + kc * 32 + quad * 8];
      for (int t = 0; t < 4; ++t)
        bfr[t] = *(const bf16x8*)&Bs[(wn + t * 16 + lc) * 64 + kc * 32 + quad * 8];
      for (int rt = 0; rt < 4; ++rt)
        for (int ct = 0; ct < 4; ++ct)
          acc[rt][ct] = __builtin_amdgcn_mfma_f32_16x16x32_bf16(
              af[rt], bfr[ct], acc[rt][ct], 0, 0, 0);
    }
  }

  const int row0 = bm * 128 + wm;
  if (epi == 0) {
    const int e0 = bn * 128;
    const int g = e0 >> 10;
    const int h = ((e0 & 1023) + wn) >> 6;
    const float qs = (g == 0) ? 0.125f * LOG2E : 1.0f;
    ushort* dst = (g == 0) ? qb : ((g == 1) ? kb : vb);
    const float ang = powf(1e-4f, (float)lc * (1.0f / 15.0f));
    for (int rt = 0; rt < 4; ++rt) {
      for (int r = 0; r < 4; ++r) {
        int m = row0 + rt * 16 + quad * 4 + r;
        int srow = m & 2047;
        int b = m >> 11;
        if (g < 2) {
          float theta = (float)srow * ang;
          float sn, c;
          sincosf(theta, &sn, &c);
          float x1 = acc[rt][0][r], x2 = acc[rt][2][r];
          acc[rt][0][r] = x1 * c - x2 * sn;
          acc[rt][2][r] = x1 * sn + x2 * c;
        }
        ushort* drow = dst + (((long)b * 16 + h) * 2048 + srow) * 64;
        for (int ct = 0; ct < 4; ++ct)
          drow[ct * 16 + lc] = f2bf(acc[rt][ct][r] * qs);
      }
    }
  } else {
    for (int rt = 0; rt < 4; ++rt)
      for (int r = 0; r < 4; ++r) {
        int m = row0 + rt * 16 + quad * 4 + r;
        float* drow = Cout + (long)m * 1024 + bn * 128 + wn;
        for (int ct = 0; ct < 4; ++ct)
          drow[ct * 16 + lc] = acc[rt][ct][r];
      }
  }
}

// ----------------------------------------------------------- V transpose
__global__ __launch_bounds__(256) void vtrans(const ushort* __restrict__ vb,
                                              ushort* __restrict__ vt) {
  __shared__ __align__(16) ushort T[64 * 72];
  const int tid = threadIdx.x, sc = blockIdx.x, bh = blockIdx.y;
  const ushort* src = vb + ((long)bh * 2048 + sc * 64) * 64;
  for (int i = 0; i < 2; ++i) {
    int u = i * 256 + tid;
    int row = u >> 3, ch = u & 7;
    uint4 vv = *(const uint4*)&src[row * 64 + ch * 8];
    const ushort* e = (const ushort*)&vv;
    for (int t = 0; t < 8; ++t) T[(ch * 8 + t) * 72 + row] = e[t];
  }
  __syncthreads();
  for (int i = 0; i < 2; ++i) {
    int u = i * 256 + tid;
    int d = u >> 3, ch = u & 7;
    uint4 vv = *(const uint4*)&T[d * 72 + ch * 8];
    *(uint4*)&vt[((long)bh * 64 + d) * 2048 + sc * 64 + ch * 8] = vv;
  }
}

// ---------------------------------------------------------------- attention
// ONE WAVE PER BLOCK, 32 q-rows. Fixed-max softmax p=exp2(s-SMAX): no running
// max, no alpha rescale -> no cross-iteration serial chain. P scratch double-
// buffered by j parity (single fence per iter).
__global__ __launch_bounds__(64) void attn_kernel(
    const ushort* __restrict__ qb, const ushort* __restrict__ kb,
    const ushort* __restrict__ vt, ushort* __restrict__ out) {
  __shared__ __align__(16) ushort Psw2[2][32 * 64];  // 8 KB, parity-buffered
  const int lane = threadIdx.x;
  const int quad = lane >> 4, lc = lane & 15, l7 = lc & 7;
  const int bid = blockIdx.x;                   // 0..2047
  const int s = 63 - (bid >> 5);                // strip, big-work first
  const int bh = bid & 31;
  const int bidx = bh >> 4, h = bh & 15;
  const int qtbase = s * 32;

  bf16x8 qf[2][2];
  for (int kc = 0; kc < 2; ++kc)
    for (int q2 = 0; q2 < 2; ++q2)
      qf[kc][q2] = *(const bf16x8*)&qb[((long)bh * 2048 + qtbase + q2 * 16 + lc) * 64 +
                                       kc * 32 + quad * 8];

  f32x4 oacc[4][2] = {};
  float l_[2] = {0.0f, 0.0f};

  const ushort* K = kb + (long)bh * 2048 * 64;
  const ushort* Vt = vt + (long)bh * 64 * 2048;
  const int jmax = s >> 1;
  const int rowoff = (s & 1) * 32;

  for (int j = 0; j <= jmax; ++j) {
    ushort* Psw = Psw2[j & 1];
    f32x4 sacc[4][2] = {};
    for (int kc = 0; kc < 2; ++kc) {
      bf16x8 kf[4];
      for (int kt = 0; kt < 4; ++kt)
        kf[kt] = *(const bf16x8*)&K[(long)(j * 64 + kt * 16 + lc) * 64 +
                                    kc * 32 + quad * 8];
      for (int kt = 0; kt < 4; ++kt)
        for (int q2 = 0; q2 < 2; ++q2)
          sacc[kt][q2] = __builtin_amdgcn_mfma_f32_16x16x32_bf16(
              kf[kt], qf[kc][q2], sacc[kt][q2], 0, 0, 0);
    }
    if (j == jmax) {  // causal partial tile
      for (int kt = 0; kt < 4; ++kt)
        for (int q2 = 0; q2 < 2; ++q2) {
          int rowrel = rowoff + q2 * 16 + lc;
          for (int r = 0; r < 4; ++r)
            if (kt * 16 + quad * 4 + r > rowrel) sacc[kt][q2][r] = -1.0e30f;
        }
    }
    // fixed-max softmax: p = exp2(s - SMAX); l += sum(p). No max, no alpha.
    for (int q2 = 0; q2 < 2; ++q2) {
      float rs = 0.0f;
      float p[4][4];
      for (int kt = 0; kt < 4; ++kt)
        for (int r = 0; r < 4; ++r) {
          p[kt][r] = exp2f(sacc[kt][q2][r] - SMAX);
          rs += p[kt][r];
        }
      rs += __shfl_xor(rs, 16, 64);
      rs += __shfl_xor(rs, 32, 64);
      l_[q2] += rs;
      for (int kt = 0; kt < 4; ++kt) {
        uint2 pk = {pack2(p[kt][0], p[kt][1]), pack2(p[kt][2], p[kt][3])};
        *(uint2*)&Psw[(q2 * 16 + lc) * 64 + (((kt * 2 + (quad >> 1)) ^ l7) << 3) +
                      ((quad & 1) << 2)] = pk;
      }
    }
    __threadfence_block();  // P writes -> P reads (same parity buffer)
    for (int kc = 0; kc < 2; ++kc) {
      bf16x8 vf[4], pf[2];
      for (int mt = 0; mt < 4; ++mt)
        vf[mt] = *(const bf16x8*)&Vt[(long)(mt * 16 + lc) * 2048 + j * 64 +
                                     kc * 32 + quad * 8];
      for (int q2 = 0; q2 < 2; ++q2)
        pf[q2] = *(const bf16x8*)&Psw[(q2 * 16 + lc) * 64 +
                                      (((kc * 4 + quad) ^ l7) << 3)];
      for (int mt = 0; mt < 4; ++mt)
        for (int q2 = 0; q2 < 2; ++q2)
          oacc[mt][q2] = __builtin_amdgcn_mfma_f32_16x16x32_bf16(
              vf[mt], pf[q2], oacc[mt][q2], 0, 0, 0);
    }
    // no second fence: next iter writes the OTHER parity buffer
  }

  // epilogue: O^T/l -> LDS -> coalesced bf16 rows of ao
  ushort* Psw = Psw2[0];
  __threadfence_block();  // last PV reads done before overwrite (parity 0 case)
  for (int q2 = 0; q2 < 2; ++q2) {
    float linv = 1.0f / l_[q2];
    for (int mt = 0; mt < 4; ++mt) {
      uint2 pk = {pack2(oacc[mt][q2][0] * linv, oacc[mt][q2][1] * linv),
                  pack2(oacc[mt][q2][2] * linv, oacc[mt][q2][3] * linv)};
      *(uint2*)&Psw[(q2 * 16 + lc) * 64 + (((mt * 2 + (quad >> 1)) ^ l7) << 3) +
                    ((quad & 1) << 2)] = pk;
    }
  }
  __threadfence_block();
  {
    int r2 = lane >> 1;
    long mrow = (long)bidx * 2048 + qtbase + r2;
    for (int c = 0; c < 4; ++c) {
      int c8 = (lane & 1) * 4 + c;
      uint4 vv = *(const uint4*)&Psw[r2 * 64 + ((c8 ^ (r2 & 7)) << 3)];
      *(uint4*)&out[mrow * 1024 + h * 64 + c8 * 8] = vv;
    }
  }
}

extern "C" void kernel_launch(void* const* d_in, const int* in_sizes, int n_in,
                              void* d_out, int out_size, void* d_ws, size_t ws_size,
                              hipStream_t stream) {
  const float* x = nullptr;     // 4194304 elems
  const float* Wqkv = nullptr;  // 3145728 elems
  const float* Wo = nullptr;    // 1048576 elems
  for (int i = 0; i < n_in; ++i) {
    if (in_sizes[i] == 4194304) x = (const float*)d_in[i];
    else if (in_sizes[i] == 3145728) Wqkv = (const float*)d_in[i];
    else if (in_sizes[i] == 1048576) Wo = (const float*)d_in[i];
  }
  float* out = (float*)d_out;  // [4096,1024] fp32 (16 MiB)

  // Workspace (32 MiB) + d_out-as-scratch timeline (same as r13):
  ushort* qbuf = (ushort*)d_ws;
  ushort* kbuf = qbuf + 4194304;
  ushort* vbuf = kbuf + 4194304;
  ushort* vtb  = vbuf + 4194304;
  ushort* wqkvh = vtb;                 // [24..30) before vtrans
  ushort* woh  = qbuf;                 // [0..2) after attn
  ushort* ao   = vbuf;                 // aliases vbuf
  ushort* xh   = (ushort*)d_out;       // x_bf16 in d_out scratch

  conv_bf16<<<2048, 256, 0, stream>>>(x, xh, 524288);
  conv_bf16<<<1536, 256, 0, stream>>>(Wqkv, wqkvh, 393216);
  gemm_bt<<<768, 256, 0, stream>>>(xh, wqkvh, 24, qbuf, kbuf, vbuf, nullptr, 0);
  vtrans<<<dim3(32, 32), 256, 0, stream>>>(vbuf, vtb);
  attn_kernel<<<2048, 64, 0, stream>>>(qbuf, kbuf, vtb, ao);
  conv_bf16<<<512, 256, 0, stream>>>(Wo, woh, 131072);
  gemm_bt<<<256, 256, 0, stream>>>(ao, woh, 8, nullptr, nullptr, nullptr, out, 1);
}

// Round 17
// 248.967 us; speedup vs baseline: 1.2025x; 1.0122x over previous
//
#include <hip/hip_runtime.h>
#include <hip/hip_bf16.h>

// B=2, S=2048, D=1024, H=16, dk=64. INPUTS FP32, OUTPUT FP32. M = 4096 rows.
// ROUND 17: de-serialize attention j-loop:
//   - compiler-only barrier (was __threadfence_block = vmcnt(0) drain!)
//   - per-lane l accumulation (no per-iter shfl)
//   - P pack via v_perm truncation (1 instr vs RNE sequence)

typedef __bf16 bf16x8 __attribute__((ext_vector_type(8)));
typedef float f32x4 __attribute__((ext_vector_type(4)));

#define LOG2E 1.4426950408889634f
#define SMAX 16.0f

__device__ __forceinline__ ushort f2bf(float f) {
  __hip_bfloat16 h = __float2bfloat16(f);
  return __builtin_bit_cast(ushort, h);
}

__device__ __forceinline__ uint pack2(float a, float b) {
  return (uint)f2bf(a) | ((uint)f2bf(b) << 16);
}

// truncating bf16x2 pack: [a.hi16 | b.hi16] in one v_perm_b32
__device__ __forceinline__ uint pack2t(float a, float b) {
  return __builtin_amdgcn_perm(__builtin_bit_cast(uint, b),
                               __builtin_bit_cast(uint, a), 0x07060302u);
}

#define CBAR() __asm__ __volatile__("" ::: "memory")

__device__ __forceinline__ void gl2lds16(const ushort* g, ushort* l) {
  __builtin_amdgcn_global_load_lds(
      (const __attribute__((address_space(1))) void*)g,
      (__attribute__((address_space(3))) void*)l, 16, 0, 0);
}

// ------------------------------------------------------------ fp32 -> bf16
__global__ __launch_bounds__(256) void conv_bf16(const float* __restrict__ src,
                                                 ushort* __restrict__ dst,
                                                 int n8) {
  int i = blockIdx.x * 256 + threadIdx.x;
  if (i >= n8) return;
  const float4* s = (const float4*)src + (long)i * 2;
  float4 a = s[0], b = s[1];
  uint4 pk = {pack2(a.x, a.y), pack2(a.z, a.w), pack2(b.x, b.y), pack2(b.z, b.w)};
  ((uint4*)dst)[i] = pk;
}

// ---------------------------------------------------------------- GEMM (NT)
// (unchanged from r13 — validated)
__global__ __launch_bounds__(256) void gemm_bt(
    const ushort* __restrict__ A, const ushort* __restrict__ B, int nbn,
    ushort* __restrict__ qb, ushort* __restrict__ kb, ushort* __restrict__ vb,
    float* __restrict__ Cout, int epi) {
  __shared__ __align__(16) ushort As[128 * 64];
  __shared__ __align__(16) ushort Bs[128 * 64];
  const int tid = threadIdx.x;
  const int w = tid >> 6, lane = tid & 63, quad = lane >> 4, lc = lane & 15;
  const int bid = blockIdx.x;
  const int bm = bid / nbn, bn = bid % nbn;
  const int wm = (w & 1) * 64, wn = (w >> 1) * 64;

  f32x4 acc[4][4] = {};

  const ushort* Ag = A + (long)bm * 131072;
  const ushort* Bg = B + (long)bn * 131072;

  for (int k0 = 0; k0 < 1024; k0 += 64) {
    __syncthreads();
    for (int i = 0; i < 4; ++i) {
      int u = i * 256 + tid;
      int row = u >> 3, ch = u & 7;
      gl2lds16(Ag + row * 1024 + k0 + ch * 8, &As[(i * 256 + w * 64) * 8]);
      gl2lds16(Bg + row * 1024 + k0 + ch * 8, &Bs[(i * 256 + w * 64) * 8]);
    }
    __builtin_amdgcn_s_waitcnt(0);
    __syncthreads();
    for (int kc = 0; kc < 2; ++kc) {
      bf16x8 af[4], bfr[4];
      for (int t = 0; t < 4; ++t)
        af[t] = *(const bf16x8*)&As[(wm + t * 16 + lc) * 64 + kc * 32 + quad * 8];
      for (int t = 0; t < 4; ++t)
        bfr[t] = *(const bf16x8*)&Bs[(wn + t * 16 + lc) * 64 + kc * 32 + quad * 8];
      for (int rt = 0; rt < 4; ++rt)
        for (int ct = 0; ct < 4; ++ct)
          acc[rt][ct] = __builtin_amdgcn_mfma_f32_16x16x32_bf16(
              af[rt], bfr[ct], acc[rt][ct], 0, 0, 0);
    }
  }

  const int row0 = bm * 128 + wm;
  if (epi == 0) {
    const int e0 = bn * 128;
    const int g = e0 >> 10;
    const int h = ((e0 & 1023) + wn) >> 6;
    const float qs = (g == 0) ? 0.125f * LOG2E : 1.0f;
    ushort* dst = (g == 0) ? qb : ((g == 1) ? kb : vb);
    const float ang = powf(1e-4f, (float)lc * (1.0f / 15.0f));
    for (int rt = 0; rt < 4; ++rt) {
      for (int r = 0; r < 4; ++r) {
        int m = row0 + rt * 16 + quad * 4 + r;
        int srow = m & 2047;
        int b = m >> 11;
        if (g < 2) {
          float theta = (float)srow * ang;
          float sn, c;
          sincosf(theta, &sn, &c);
          float x1 = acc[rt][0][r], x2 = acc[rt][2][r];
          acc[rt][0][r] = x1 * c - x2 * sn;
          acc[rt][2][r] = x1 * sn + x2 * c;
        }
        ushort* drow = dst + (((long)b * 16 + h) * 2048 + srow) * 64;
        for (int ct = 0; ct < 4; ++ct)
          drow[ct * 16 + lc] = f2bf(acc[rt][ct][r] * qs);
      }
    }
  } else {
    for (int rt = 0; rt < 4; ++rt)
      for (int r = 0; r < 4; ++r) {
        int m = row0 + rt * 16 + quad * 4 + r;
        float* drow = Cout + (long)m * 1024 + bn * 128 + wn;
        for (int ct = 0; ct < 4; ++ct)
          drow[ct * 16 + lc] = acc[rt][ct][r];
      }
  }
}

// ----------------------------------------------------------- V transpose
__global__ __launch_bounds__(256) void vtrans(const ushort* __restrict__ vb,
                                              ushort* __restrict__ vt) {
  __shared__ __align__(16) ushort T[64 * 72];
  const int tid = threadIdx.x, sc = blockIdx.x, bh = blockIdx.y;
  const ushort* src = vb + ((long)bh * 2048 + sc * 64) * 64;
  for (int i = 0; i < 2; ++i) {
    int u = i * 256 + tid;
    int row = u >> 3, ch = u & 7;
    uint4 vv = *(const uint4*)&src[row * 64 + ch * 8];
    const ushort* e = (const ushort*)&vv;
    for (int t = 0; t < 8; ++t) T[(ch * 8 + t) * 72 + row] = e[t];
  }
  __syncthreads();
  for (int i = 0; i < 2; ++i) {
    int u = i * 256 + tid;
    int d = u >> 3, ch = u & 7;
    uint4 vv = *(const uint4*)&T[d * 72 + ch * 8];
    *(uint4*)&vt[((long)bh * 64 + d) * 2048 + sc * 64 + ch * 8] = vv;
  }
}

// ---------------------------------------------------------------- attention
// ONE WAVE PER BLOCK, 32 q-rows. Fixed-max softmax (p = exp2(s-SMAX)),
// per-lane l accumulation, parity-buffered P, COMPILER-ONLY barriers
// (HW DS pipe is in-order per wave; no vmcnt drain -> K/Vt prefetch lives).
__global__ __launch_bounds__(64) void attn_kernel(
    const ushort* __restrict__ qb, const ushort* __restrict__ kb,
    const ushort* __restrict__ vt, ushort* __restrict__ out) {
  __shared__ __align__(16) ushort Psw2[2][32 * 64];
  const int lane = threadIdx.x;
  const int quad = lane >> 4, lc = lane & 15, l7 = lc & 7;
  const int bid = blockIdx.x;                   // 0..2047
  const int s = 63 - (bid >> 5);                // strip, big-work first
  const int bh = bid & 31;
  const int bidx = bh >> 4, h = bh & 15;
  const int qtbase = s * 32;

  bf16x8 qf[2][2];
  for (int kc = 0; kc < 2; ++kc)
    for (int q2 = 0; q2 < 2; ++q2)
      qf[kc][q2] = *(const bf16x8*)&qb[((long)bh * 2048 + qtbase + q2 * 16 + lc) * 64 +
                                       kc * 32 + quad * 8];

  f32x4 oacc[4][2] = {};
  float l_lane[2] = {0.0f, 0.0f};  // per-lane partial (16 keys/lane/iter)

  const ushort* K = kb + (long)bh * 2048 * 64;
  const ushort* Vt = vt + (long)bh * 64 * 2048;
  const int jmax = s >> 1;
  const int rowoff = (s & 1) * 32;

  for (int j = 0; j <= jmax; ++j) {
    ushort* Psw = Psw2[j & 1];
    f32x4 sacc[4][2] = {};
    for (int kc = 0; kc < 2; ++kc) {
      bf16x8 kf[4];
      for (int kt = 0; kt < 4; ++kt)
        kf[kt] = *(const bf16x8*)&K[(long)(j * 64 + kt * 16 + lc) * 64 +
                                    kc * 32 + quad * 8];
      for (int kt = 0; kt < 4; ++kt)
        for (int q2 = 0; q2 < 2; ++q2)
          sacc[kt][q2] = __builtin_amdgcn_mfma_f32_16x16x32_bf16(
              kf[kt], qf[kc][q2], sacc[kt][q2], 0, 0, 0);
    }
    if (j == jmax) {  // causal partial tile
      for (int kt = 0; kt < 4; ++kt)
        for (int q2 = 0; q2 < 2; ++q2) {
          int rowrel = rowoff + q2 * 16 + lc;
          for (int r = 0; r < 4; ++r)
            if (kt * 16 + quad * 4 + r > rowrel) sacc[kt][q2][r] = -1.0e30f;
        }
    }
    for (int q2 = 0; q2 < 2; ++q2) {
      float p[4][4];
      float rs = 0.0f;
      for (int kt = 0; kt < 4; ++kt)
        for (int r = 0; r < 4; ++r) {
          p[kt][r] = exp2f(sacc[kt][q2][r] - SMAX);
          rs += p[kt][r];
        }
      l_lane[q2] += rs;  // cross-lane reduce deferred to epilogue
      for (int kt = 0; kt < 4; ++kt) {
        uint2 pk = {pack2t(p[kt][0], p[kt][1]), pack2t(p[kt][2], p[kt][3])};
        *(uint2*)&Psw[(q2 * 16 + lc) * 64 + (((kt * 2 + (quad >> 1)) ^ l7) << 3) +
                      ((quad & 1) << 2)] = pk;
      }
    }
    CBAR();  // compiler-only: P writes ordered before P reads (HW DS in-order)
    for (int kc = 0; kc < 2; ++kc) {
      bf16x8 vf[4], pf[2];
      for (int mt = 0; mt < 4; ++mt)
        vf[mt] = *(const bf16x8*)&Vt[(long)(mt * 16 + lc) * 2048 + j * 64 +
                                     kc * 32 + quad * 8];
      for (int q2 = 0; q2 < 2; ++q2)
        pf[q2] = *(const bf16x8*)&Psw[(q2 * 16 + lc) * 64 +
                                      (((kc * 4 + quad) ^ l7) << 3)];
      for (int mt = 0; mt < 4; ++mt)
        for (int q2 = 0; q2 < 2; ++q2)
          oacc[mt][q2] = __builtin_amdgcn_mfma_f32_16x16x32_bf16(
              vf[mt], pf[q2], oacc[mt][q2], 0, 0, 0);
    }
    CBAR();  // keep compiler from sinking P reads below next-iter writes
  }

  // epilogue: reduce l across quads (once), normalize, store via LDS
  float l_[2];
  for (int q2 = 0; q2 < 2; ++q2) {
    float rs = l_lane[q2];
    rs += __shfl_xor(rs, 16, 64);
    rs += __shfl_xor(rs, 32, 64);
    l_[q2] = rs;
  }
  ushort* Psw = Psw2[0];
  CBAR();
  for (int q2 = 0; q2 < 2; ++q2) {
    float linv = 1.0f / l_[q2];
    for (int mt = 0; mt < 4; ++mt) {
      uint2 pk = {pack2(oacc[mt][q2][0] * linv, oacc[mt][q2][1] * linv),
                  pack2(oacc[mt][q2][2] * linv, oacc[mt][q2][3] * linv)};
      *(uint2*)&Psw[(q2 * 16 + lc) * 64 + (((mt * 2 + (quad >> 1)) ^ l7) << 3) +
                    ((quad & 1) << 2)] = pk;
    }
  }
  CBAR();
  {
    int r2 = lane >> 1;
    long mrow = (long)bidx * 2048 + qtbase + r2;
    for (int c = 0; c < 4; ++c) {
      int c8 = (lane & 1) * 4 + c;
      uint4 vv = *(const uint4*)&Psw[r2 * 64 + ((c8 ^ (r2 & 7)) << 3)];
      *(uint4*)&out[mrow * 1024 + h * 64 + c8 * 8] = vv;
    }
  }
}

extern "C" void kernel_launch(void* const* d_in, const int* in_sizes, int n_in,
                              void* d_out, int out_size, void* d_ws, size_t ws_size,
                              hipStream_t stream) {
  const float* x = nullptr;     // 4194304 elems
  const float* Wqkv = nullptr;  // 3145728 elems
  const float* Wo = nullptr;    // 1048576 elems
  for (int i = 0; i < n_in; ++i) {
    if (in_sizes[i] == 4194304) x = (const float*)d_in[i];
    else if (in_sizes[i] == 3145728) Wqkv = (const float*)d_in[i];
    else if (in_sizes[i] == 1048576) Wo = (const float*)d_in[i];
  }
  float* out = (float*)d_out;  // [4096,1024] fp32 (16 MiB)

  // Workspace (32 MiB) + d_out-as-scratch timeline (same as r13):
  ushort* qbuf = (ushort*)d_ws;
  ushort* kbuf = qbuf + 4194304;
  ushort* vbuf = kbuf + 4194304;
  ushort* vtb  = vbuf + 4194304;
  ushort* wqkvh = vtb;                 // [24..30) before vtrans
  ushort* woh  = qbuf;                 // [0..2) after attn
  ushort* ao   = vbuf;                 // aliases vbuf
  ushort* xh   = (ushort*)d_out;       // x_bf16 in d_out scratch

  conv_bf16<<<2048, 256, 0, stream>>>(x, xh, 524288);
  conv_bf16<<<1536, 256, 0, stream>>>(Wqkv, wqkvh, 393216);
  gemm_bt<<<768, 256, 0, stream>>>(xh, wqkvh, 24, qbuf, kbuf, vbuf, nullptr, 0);
  vtrans<<<dim3(32, 32), 256, 0, stream>>>(vbuf, vtb);
  attn_kernel<<<2048, 64, 0, stream>>>(qbuf, kbuf, vtb, ao);
  conv_bf16<<<512, 256, 0, stream>>>(Wo, woh, 131072);
  gemm_bt<<<256, 256, 0, stream>>>(ao, woh, 8, nullptr, nullptr, nullptr, out, 1);
}

// Round 18
// 237.527 us; speedup vs baseline: 1.2604x; 1.0482x over previous
//
#include <hip/hip_runtime.h>
#include <hip/hip_bf16.h>

// B=2, S=2048, D=1024, H=16, dk=64. INPUTS FP32, OUTPUT FP32. M = 4096 rows.
// ROUND 18: software-pipelined attention j-loop — K/Vt tiles prefetched into
// registers ONE ITERATION AHEAD (loads get ~1 full iter to land; waitcnt
// before use drains only older loads). Single CBAR per iter (parity WAR is
// 2 iters apart; HW DS pipe is in-order per wave).

typedef __bf16 bf16x8 __attribute__((ext_vector_type(8)));
typedef float f32x4 __attribute__((ext_vector_type(4)));

#define LOG2E 1.4426950408889634f
#define SMAX 16.0f

__device__ __forceinline__ ushort f2bf(float f) {
  __hip_bfloat16 h = __float2bfloat16(f);
  return __builtin_bit_cast(ushort, h);
}

__device__ __forceinline__ uint pack2(float a, float b) {
  return (uint)f2bf(a) | ((uint)f2bf(b) << 16);
}

// truncating bf16x2 pack in one v_perm_b32
__device__ __forceinline__ uint pack2t(float a, float b) {
  return __builtin_amdgcn_perm(__builtin_bit_cast(uint, b),
                               __builtin_bit_cast(uint, a), 0x07060302u);
}

#define CBAR() __asm__ __volatile__("" ::: "memory")

__device__ __forceinline__ void gl2lds16(const ushort* g, ushort* l) {
  __builtin_amdgcn_global_load_lds(
      (const __attribute__((address_space(1))) void*)g,
      (__attribute__((address_space(3))) void*)l, 16, 0, 0);
}

// ------------------------------------------------------------ fp32 -> bf16
__global__ __launch_bounds__(256) void conv_bf16(const float* __restrict__ src,
                                                 ushort* __restrict__ dst,
                                                 int n8) {
  int i = blockIdx.x * 256 + threadIdx.x;
  if (i >= n8) return;
  const float4* s = (const float4*)src + (long)i * 2;
  float4 a = s[0], b = s[1];
  uint4 pk = {pack2(a.x, a.y), pack2(a.z, a.w), pack2(b.x, b.y), pack2(b.z, b.w)};
  ((uint4*)dst)[i] = pk;
}

// ---------------------------------------------------------------- GEMM (NT)
// (unchanged from r13 — validated)
__global__ __launch_bounds__(256) void gemm_bt(
    const ushort* __restrict__ A, const ushort* __restrict__ B, int nbn,
    ushort* __restrict__ qb, ushort* __restrict__ kb, ushort* __restrict__ vb,
    float* __restrict__ Cout, int epi) {
  __shared__ __align__(16) ushort As[128 * 64];
  __shared__ __align__(16) ushort Bs[128 * 64];
  const int tid = threadIdx.x;
  const int w = tid >> 6, lane = tid & 63, quad = lane >> 4, lc = lane & 15;
  const int bid = blockIdx.x;
  const int bm = bid / nbn, bn = bid % nbn;
  const int wm = (w & 1) * 64, wn = (w >> 1) * 64;

  f32x4 acc[4][4] = {};

  const ushort* Ag = A + (long)bm * 131072;
  const ushort* Bg = B + (long)bn * 131072;

  for (int k0 = 0; k0 < 1024; k0 += 64) {
    __syncthreads();
    for (int i = 0; i < 4; ++i) {
      int u = i * 256 + tid;
      int row = u >> 3, ch = u & 7;
      gl2lds16(Ag + row * 1024 + k0 + ch * 8, &As[(i * 256 + w * 64) * 8]);
      gl2lds16(Bg + row * 1024 + k0 + ch * 8, &Bs[(i * 256 + w * 64) * 8]);
    }
    __builtin_amdgcn_s_waitcnt(0);
    __syncthreads();
    for (int kc = 0; kc < 2; ++kc) {
      bf16x8 af[4], bfr[4];
      for (int t = 0; t < 4; ++t)
        af[t] = *(const bf16x8*)&As[(wm + t * 16 + lc) * 64 + kc * 32 + quad * 8];
      for (int t = 0; t < 4; ++t)
        bfr[t] = *(const bf16x8*)&Bs[(wn + t * 16 + lc) * 64 + kc * 32 + quad * 8];
      for (int rt = 0; rt < 4; ++rt)
        for (int ct = 0; ct < 4; ++ct)
          acc[rt][ct] = __builtin_amdgcn_mfma_f32_16x16x32_bf16(
              af[rt], bfr[ct], acc[rt][ct], 0, 0, 0);
    }
  }

  const int row0 = bm * 128 + wm;
  if (epi == 0) {
    const int e0 = bn * 128;
    const int g = e0 >> 10;
    const int h = ((e0 & 1023) + wn) >> 6;
    const float qs = (g == 0) ? 0.125f * LOG2E : 1.0f;
    ushort* dst = (g == 0) ? qb : ((g == 1) ? kb : vb);
    const float ang = powf(1e-4f, (float)lc * (1.0f / 15.0f));
    for (int rt = 0; rt < 4; ++rt) {
      for (int r = 0; r < 4; ++r) {
        int m = row0 + rt * 16 + quad * 4 + r;
        int srow = m & 2047;
        int b = m >> 11;
        if (g < 2) {
          float theta = (float)srow * ang;
          float sn, c;
          sincosf(theta, &sn, &c);
          float x1 = acc[rt][0][r], x2 = acc[rt][2][r];
          acc[rt][0][r] = x1 * c - x2 * sn;
          acc[rt][2][r] = x1 * sn + x2 * c;
        }
        ushort* drow = dst + (((long)b * 16 + h) * 2048 + srow) * 64;
        for (int ct = 0; ct < 4; ++ct)
          drow[ct * 16 + lc] = f2bf(acc[rt][ct][r] * qs);
      }
    }
  } else {
    for (int rt = 0; rt < 4; ++rt)
      for (int r = 0; r < 4; ++r) {
        int m = row0 + rt * 16 + quad * 4 + r;
        float* drow = Cout + (long)m * 1024 + bn * 128 + wn;
        for (int ct = 0; ct < 4; ++ct)
          drow[ct * 16 + lc] = acc[rt][ct][r];
      }
  }
}

// ----------------------------------------------------------- V transpose
__global__ __launch_bounds__(256) void vtrans(const ushort* __restrict__ vb,
                                              ushort* __restrict__ vt) {
  __shared__ __align__(16) ushort T[64 * 72];
  const int tid = threadIdx.x, sc = blockIdx.x, bh = blockIdx.y;
  const ushort* src = vb + ((long)bh * 2048 + sc * 64) * 64;
  for (int i = 0; i < 2; ++i) {
    int u = i * 256 + tid;
    int row = u >> 3, ch = u & 7;
    uint4 vv = *(const uint4*)&src[row * 64 + ch * 8];
    const ushort* e = (const ushort*)&vv;
    for (int t = 0; t < 8; ++t) T[(ch * 8 + t) * 72 + row] = e[t];
  }
  __syncthreads();
  for (int i = 0; i < 2; ++i) {
    int u = i * 256 + tid;
    int d = u >> 3, ch = u & 7;
    uint4 vv = *(const uint4*)&T[d * 72 + ch * 8];
    *(uint4*)&vt[((long)bh * 64 + d) * 2048 + sc * 64 + ch * 8] = vv;
  }
}

// ---------------------------------------------------------------- attention
// ONE WAVE PER BLOCK, 32 q-rows. Fixed-max softmax, per-lane l, parity P.
// SOFTWARE PIPELINED: kf/vf for iter j are loaded at the top of iter j-1.
__global__ __launch_bounds__(64) void attn_kernel(
    const ushort* __restrict__ qb, const ushort* __restrict__ kb,
    const ushort* __restrict__ vt, ushort* __restrict__ out) {
  __shared__ __align__(16) ushort Psw2[2][32 * 64];
  const int lane = threadIdx.x;
  const int quad = lane >> 4, lc = lane & 15, l7 = lc & 7;
  const int bid = blockIdx.x;                   // 0..2047
  const int s = 63 - (bid >> 5);                // strip, big-work first
  const int bh = bid & 31;
  const int bidx = bh >> 4, h = bh & 15;
  const int qtbase = s * 32;

  bf16x8 qf[2][2];
  for (int kc = 0; kc < 2; ++kc)
    for (int q2 = 0; q2 < 2; ++q2)
      qf[kc][q2] = *(const bf16x8*)&qb[((long)bh * 2048 + qtbase + q2 * 16 + lc) * 64 +
                                       kc * 32 + quad * 8];

  f32x4 oacc[4][2] = {};
  float l_lane[2] = {0.0f, 0.0f};

  const ushort* K = kb + (long)bh * 2048 * 64;
  const ushort* Vt = vt + (long)bh * 64 * 2048;
  const int jmax = s >> 1;
  const int rowoff = (s & 1) * 32;

  // prologue: load tile 0
  bf16x8 kfc[2][4], vfc[2][4];
  for (int kc = 0; kc < 2; ++kc)
    for (int t = 0; t < 4; ++t) {
      kfc[kc][t] = *(const bf16x8*)&K[(long)(t * 16 + lc) * 64 + kc * 32 + quad * 8];
      vfc[kc][t] = *(const bf16x8*)&Vt[(long)(t * 16 + lc) * 2048 + kc * 32 + quad * 8];
    }

  for (int j = 0; j <= jmax; ++j) {
    ushort* Psw = Psw2[j & 1];
    // prefetch next tile (clamped; loads have the whole iter to land)
    int jn = (j < jmax) ? j + 1 : j;
    bf16x8 kfn[2][4], vfn[2][4];
    for (int kc = 0; kc < 2; ++kc)
      for (int t = 0; t < 4; ++t) {
        kfn[kc][t] = *(const bf16x8*)&K[(long)(jn * 64 + t * 16 + lc) * 64 +
                                       kc * 32 + quad * 8];
        vfn[kc][t] = *(const bf16x8*)&Vt[(long)(t * 16 + lc) * 2048 + jn * 64 +
                                         kc * 32 + quad * 8];
      }

    f32x4 sacc[4][2] = {};
    for (int kc = 0; kc < 2; ++kc)
      for (int kt = 0; kt < 4; ++kt)
        for (int q2 = 0; q2 < 2; ++q2)
          sacc[kt][q2] = __builtin_amdgcn_mfma_f32_16x16x32_bf16(
              kfc[kc][kt], qf[kc][q2], sacc[kt][q2], 0, 0, 0);

    if (j == jmax) {  // causal partial tile
      for (int kt = 0; kt < 4; ++kt)
        for (int q2 = 0; q2 < 2; ++q2) {
          int rowrel = rowoff + q2 * 16 + lc;
          for (int r = 0; r < 4; ++r)
            if (kt * 16 + quad * 4 + r > rowrel) sacc[kt][q2][r] = -1.0e30f;
        }
    }
    for (int q2 = 0; q2 < 2; ++q2) {
      float p[4][4];
      float rs = 0.0f;
      for (int kt = 0; kt < 4; ++kt)
        for (int r = 0; r < 4; ++r) {
          p[kt][r] = exp2f(sacc[kt][q2][r] - SMAX);
          rs += p[kt][r];
        }
      l_lane[q2] += rs;
      for (int kt = 0; kt < 4; ++kt) {
        uint2 pk = {pack2t(p[kt][0], p[kt][1]), pack2t(p[kt][2], p[kt][3])};
        *(uint2*)&Psw[(q2 * 16 + lc) * 64 + (((kt * 2 + (quad >> 1)) ^ l7) << 3) +
                      ((quad & 1) << 2)] = pk;
      }
    }
    CBAR();  // compiler-only: P writes before P reads (HW DS in-order)
    for (int kc = 0; kc < 2; ++kc) {
      bf16x8 pf[2];
      for (int q2 = 0; q2 < 2; ++q2)
        pf[q2] = *(const bf16x8*)&Psw[(q2 * 16 + lc) * 64 +
                                      (((kc * 4 + quad) ^ l7) << 3)];
      for (int mt = 0; mt < 4; ++mt)
        for (int q2 = 0; q2 < 2; ++q2)
          oacc[mt][q2] = __builtin_amdgcn_mfma_f32_16x16x32_bf16(
              vfc[kc][mt], pf[q2], oacc[mt][q2], 0, 0, 0);
    }
    // rotate prefetched tiles into current
    for (int kc = 0; kc < 2; ++kc)
      for (int t = 0; t < 4; ++t) {
        kfc[kc][t] = kfn[kc][t];
        vfc[kc][t] = vfn[kc][t];
      }
  }

  // epilogue: reduce l across quads, normalize, store via LDS
  float l_[2];
  for (int q2 = 0; q2 < 2; ++q2) {
    float rs = l_lane[q2];
    rs += __shfl_xor(rs, 16, 64);
    rs += __shfl_xor(rs, 32, 64);
    l_[q2] = rs;
  }
  ushort* Psw = Psw2[0];
  CBAR();
  for (int q2 = 0; q2 < 2; ++q2) {
    float linv = 1.0f / l_[q2];
    for (int mt = 0; mt < 4; ++mt) {
      uint2 pk = {pack2(oacc[mt][q2][0] * linv, oacc[mt][q2][1] * linv),
                  pack2(oacc[mt][q2][2] * linv, oacc[mt][q2][3] * linv)};
      *(uint2*)&Psw[(q2 * 16 + lc) * 64 + (((mt * 2 + (quad >> 1)) ^ l7) << 3) +
                    ((quad & 1) << 2)] = pk;
    }
  }
  CBAR();
  {
    int r2 = lane >> 1;
    long mrow = (long)bidx * 2048 + qtbase + r2;
    for (int c = 0; c < 4; ++c) {
      int c8 = (lane & 1) * 4 + c;
      uint4 vv = *(const uint4*)&Psw[r2 * 64 + ((c8 ^ (r2 & 7)) << 3)];
      *(uint4*)&out[mrow * 1024 + h * 64 + c8 * 8] = vv;
    }
  }
}

extern "C" void kernel_launch(void* const* d_in, const int* in_sizes, int n_in,
                              void* d_out, int out_size, void* d_ws, size_t ws_size,
                              hipStream_t stream) {
  const float* x = nullptr;     // 4194304 elems
  const float* Wqkv = nullptr;  // 3145728 elems
  const float* Wo = nullptr;    // 1048576 elems
  for (int i = 0; i < n_in; ++i) {
    if (in_sizes[i] == 4194304) x = (const float*)d_in[i];
    else if (in_sizes[i] == 3145728) Wqkv = (const float*)d_in[i];
    else if (in_sizes[i] == 1048576) Wo = (const float*)d_in[i];
  }
  float* out = (float*)d_out;  // [4096,1024] fp32 (16 MiB)

  // Workspace (32 MiB) + d_out-as-scratch timeline (same as r13):
  ushort* qbuf = (ushort*)d_ws;
  ushort* kbuf = qbuf + 4194304;
  ushort* vbuf = kbuf + 4194304;
  ushort* vtb  = vbuf + 4194304;
  ushort* wqkvh = vtb;                 // [24..30) before vtrans
  ushort* woh  = qbuf;                 // [0..2) after attn
  ushort* ao   = vbuf;                 // aliases vbuf
  ushort* xh   = (ushort*)d_out;       // x_bf16 in d_out scratch

  conv_bf16<<<2048, 256, 0, stream>>>(x, xh, 524288);
  conv_bf16<<<1536, 256, 0, stream>>>(Wqkv, wqkvh, 393216);
  gemm_bt<<<768, 256, 0, stream>>>(xh, wqkvh, 24, qbuf, kbuf, vbuf, nullptr, 0);
  vtrans<<<dim3(32, 32), 256, 0, stream>>>(vbuf, vtb);
  attn_kernel<<<2048, 64, 0, stream>>>(qbuf, kbuf, vtb, ao);
  conv_bf16<<<512, 256, 0, stream>>>(Wo, woh, 131072);
  gemm_bt<<<256, 256, 0, stream>>>(ao, woh, 8, nullptr, nullptr, nullptr, out, 1);
}